// Round 19
// baseline (49.885 us; speedup 1.0000x reference)
//
#include <hip/hip_runtime.h>

// Batched Thomas tridiagonal solve, B=8192 rows, N=4096.
//   a_i = alpha[i-1]^2 (a_0=0); b_i = max(5+alpha[i]^3, 0.01);
//   c_i = alpha[i+1]^2 + 2*alpha[i+1]; rhs f (shared across rows).
//
// Chunked UL elimination with halos (right halo 8, left halo 8).
//
// R19: R18 + global_load_lds staging. R18 still did global->VGPR->LDS with
// unroll-3 (3 loads in flight, 2 extra waits). Now: 12 fire-and-forget
// glds16 ops, one vmcnt(0). Key enabler: ST4=69 unpadded satisfies BOTH the
// glds linear-dest constraint (dest=idx*16, idx=row*69+c4) AND zero-conflict
// compute reads (276 dw row stride == 20 mod 32 -> quarter-wave's 8 rows
// cover all 32 banks). R8's glds failure causes (1-wave occupancy, stride-16
// conflicts) are absent here. Math identical to R18 (absmax 0.0078125).

namespace {
constexpr int kCH  = 32;              // outputs per lane
constexpr int kHL  = 8;               // left halo
constexpr int kR   = kCH + kHL;       // stored region = 40 (groups 0..9)
constexpr int kNC  = 128;             // chunks per row
constexpr int RPW  = 8;               // rows per block (shared by both waves)
constexpr int THREADS = 128;          // 2 waves
constexpr int F4PR = 69;              // staged f4/row: cols [cb-12, cb+264)
constexpr int ST4  = 69;              // UNPADDED: glds-linear + conflict-free
constexpr int APW4 = RPW * ST4;       // 552 f4 per wave panel
constexpr int SF4  = 133;             // f pair window
constexpr int GHI  = 11;              // top group (halo groups 10..11)
}

using f4v = float __attribute__((ext_vector_type(4)));
using h2v = __fp16 __attribute__((ext_vector_type(2)));

__device__ __forceinline__ void glds16(const float4* g, float4* l) {
  __builtin_amdgcn_global_load_lds(
      (const __attribute__((address_space(1))) unsigned int*)g,
      (__attribute__((address_space(3))) unsigned int*)l, 16, 0, 0);
}

__global__ __launch_bounds__(THREADS, 3) void thomas_v19(
    const float4* __restrict__ alpha4,
    const float4* __restrict__ f4,
    float4* __restrict__ u4)
{
  __shared__ float4 sM[2 * APW4 + SF4];   // 1237 f4 = 19792 B

  const int bid  = blockIdx.x;
  const int pair = bid & 7;                 // 512-col window pair
  const int rw0  = (bid >> 3) * RPW;        // 8 rows, shared by both waves
  const int w    = threadIdx.x >> 6;        // wave id: tile 2*pair+w
  const int lane = threadIdx.x & 63;
  const int j    = lane & 7;                // row-local (quarter-wave: 8 rows)
  const int q    = lane >> 3;               // chunk-local 0..7
  const int cw   = pair * 2 + w;            // this wave's 256-col window

  float4* __restrict__ sA = sM + w * APW4;  // wave-private [RPW][69], linear
  float4* __restrict__ sF = sM + 2 * APW4;  // f window (identical-value race ok)

  // ---- fire-and-forget staging: 12 global_load_lds, zero VGPR round-trip ----
  {
    const int fb4 = pair * 128 - 3;
    #pragma unroll
    for (int it = 0; it < 3; ++it) {
      const int idx = lane + it * 64;
      if (idx < SF4) {
        int g4 = fb4 + idx;
        g4 = (g4 < 0) ? 0 : ((g4 > 1023) ? 1023 : g4);
        glds16(f4 + g4, sF + it * 64);    // HW: dest + lane*16
      }
    }
  }
  {
    const int cb4 = cw * 64 - 3;
    #pragma unroll
    for (int it = 0; it < 9; ++it) {
      const int idx = lane + it * 64;
      if (idx < RPW * F4PR) {             // 552; it=8 has 40 active lanes
        const int row = idx / F4PR;
        const int c4  = idx - row * F4PR;
        int g4 = cb4 + c4;
        g4 = (g4 < 0) ? 0 : ((g4 > 1023) ? 1023 : g4);  // dups unused
        glds16(alpha4 + (size_t)(rw0 + row) * 1024 + g4, sA + it * 64);
      }
    }
  }
  asm volatile("s_waitcnt vmcnt(0)" ::: "memory");
  __builtin_amdgcn_sched_barrier(0);      // rule #18: pin dependent ds_reads
  // no __syncthreads: wave reads only its own sA + the shared sF it also
  // wrote (both waves write identical sF bytes; lockstep ordering)

#define STEP(am1v, fiv)                                        \
  {                                                            \
    const float c_  = ap1 * (ap1 + 2.0f);                      \
    const float b_  = fmaxf(fmaf(a0 * a0, a0, 5.0f), 0.01f);   \
    const float dn  = fmaf(-c_, ec, b_);                       \
    const float rd  = __builtin_amdgcn_rcpf(dn);               \
    gc = (fiv - c_ * gc) * rd;                                 \
    ec = ((am1v) * (am1v)) * rd;                               \
    ap1 = a0; a0 = (am1v);                                     \
  }

  // ---- solve this wave's tile ----
  const int  kk    = cw * 8 + q;
  const bool first = (kk == 0);
  const bool last  = (kk == kNC - 1);
  const int  f4b   = first ? 3 : (q * 8 + 1);
  const int  fOff  = w * 64;
  const float4* __restrict__ A4 = sA + j * ST4;

  h2v gp_pk[kR / 2], ep_pk[kR / 2];     // fp16-packed stores: 40 regs
  float ec = 0.0f, gc = 0.0f, ap1 = 0.0f;
  const int ghi = last ? 9 : GHI;
  float4 curA = A4[f4b + ghi];
  float4 lowA = A4[f4b + ghi - 1];
  float4 fcur = sF[fOff + f4b + ghi];
  float4 flow = sF[fOff + f4b + ghi - 1];
  float a0 = curA.w;

  if (!last) {
    #pragma unroll
    for (int g = GHI; g >= 10; --g) {
      const float4 pA = A4[f4b + g - 2];
      const float4 pF = sF[fOff + f4b + g - 2];
      STEP(curA.z, fcur.w)
      STEP(curA.y, fcur.z)
      STEP(curA.x, fcur.y)
      STEP(lowA.w, fcur.x)
      curA = lowA; lowA = pA; fcur = flow; flow = pF;
    }
  }

  #pragma unroll
  for (int g = 9; g >= 0; --g) {
    int pidx = f4b + g - 2;
    if (pidx < 0) pidx = 0;              // value unused when clamped
    const float4 pA = A4[pidx];
    const float4 pF = sF[fOff + pidx];
    float lw = lowA.w;
    if (g == 0 && first) lw = 0.0f;      // a_0 = 0
    STEP(curA.z, fcur.w)  const float g3_ = gc, e3_ = ec;
    STEP(curA.y, fcur.z)  const float g2_ = gc, e2_ = ec;
    STEP(curA.x, fcur.y)  const float g1_ = gc, e1_ = ec;
    STEP(lw,     fcur.x)  const float g0_ = gc, e0_ = ec;
    gp_pk[2 * g + 1] = __builtin_amdgcn_cvt_pkrtz(g2_, g3_);
    gp_pk[2 * g]     = __builtin_amdgcn_cvt_pkrtz(g0_, g1_);
    ep_pk[2 * g + 1] = __builtin_amdgcn_cvt_pkrtz(e2_, e3_);
    ep_pk[2 * g]     = __builtin_amdgcn_cvt_pkrtz(e0_, e1_);
    curA = lowA; lowA = pA; fcur = flow; flow = pF;
  }

  // ---- substitution into own panel (overlays sA), then nt dump ----
  const int tmin = first ? 0 : kHL;
  float up = 0.0f;
  float4 pk;
  #pragma unroll
  for (int t = 0; t < kR; ++t) {
    const float gpv = (float)gp_pk[t >> 1][t & 1];
    const float epv = (float)ep_pk[t >> 1][t & 1];
    const float uv = fmaf(-epv, up, gpv);
    up = uv;
    const int ph = t & 3;
    if      (ph == 0) pk.x = uv;
    else if (ph == 1) pk.y = uv;
    else if (ph == 2) pk.z = uv;
    else {
      pk.w = uv;
      if (t - 3 >= tmin && t < tmin + kCH) {
        sA[j * ST4 + q * 8 + ((t - 3 - tmin) >> 2)] = pk;
      }
    }
  }

  #pragma unroll
  for (int it = 0; it < RPW; ++it) {
    const float4 v = sA[it * ST4 + lane];
    f4v vv; vv.x = v.x; vv.y = v.y; vv.z = v.z; vv.w = v.w;
    __builtin_nontemporal_store(vv, reinterpret_cast<f4v*>(
        u4 + (size_t)(rw0 + it) * 1024 + cw * 64 + lane));
  }

#undef STEP
}

extern "C" void kernel_launch(void* const* d_in, const int* in_sizes, int n_in,
                              void* d_out, int out_size, void* d_ws, size_t ws_size,
                              hipStream_t stream) {
  const float4* alpha = (const float4*)d_in[0];
  const float4* f     = (const float4*)d_in[1];
  float4*       uo    = (float4*)d_out;
  // grid: 1024 row-groups (8 rows) x 8 window-pairs (512 cols) = 8192 blocks
  thomas_v19<<<dim3(8192), THREADS, 0, stream>>>(alpha, f, uo);
}

// Round 20
// 49.361 us; speedup vs baseline: 1.0106x; 1.0106x over previous
//
#include <hip/hip_runtime.h>

// Batched Thomas tridiagonal solve, B=8192 rows, N=4096.
//   a_i = alpha[i-1]^2 (a_0=0); b_i = max(5+alpha[i]^3, 0.01);
//   c_i = alpha[i+1]^2 + 2*alpha[i+1]; rhs f (shared across rows).
//
// Chunked UL elimination with halos (right halo 8, left halo 8).
//
// R20: division-free Mobius chain. R18's residual ~14us is rcp-on-chain
// latency (fma->rcp->mul ~28 cyc x 96 steps/wave). Unnormalized form:
//   D_i = b'·D − c'·N ; N_i = a'²·D ; P_i = f'·D − c'·P   (all x1/8 scale)
// ec=N/D, gc=P/D computed only at 40 stored positions (independent,
// off-chain rcps). Chain 28->12 cyc/step; D decays in [1e-13,1] (f32-safe,
// ratios scale-invariant, no cancellation: c·N/(b·D)<=0.15). Everything
// else identical to R18 (best, 48.2us). absmax expected ~0.008.

namespace {
constexpr int kCH  = 32;              // outputs per lane
constexpr int kHL  = 8;               // left halo
constexpr int kR   = kCH + kHL;       // stored region = 40 (groups 0..9)
constexpr int kNC  = 128;             // chunks per row
constexpr int RPW  = 8;               // rows per block (shared by both waves)
constexpr int THREADS = 128;          // 2 waves
constexpr int F4PR = 69;              // staged f4/row: cols [cb-12, cb+264)
constexpr int ST4  = 71;              // A row stride in f4 (284 dw; %32==28)
constexpr int APW4 = RPW * ST4;       // 568 f4 per wave panel
constexpr int SF4  = 133;             // f pair window
constexpr int GHI  = 11;              // top group (halo groups 10..11)
}

using f4v = float __attribute__((ext_vector_type(4)));
using h2v = __fp16 __attribute__((ext_vector_type(2)));

__global__ __launch_bounds__(THREADS, 3) void thomas_v20(
    const float4* __restrict__ alpha4,
    const float4* __restrict__ f4,
    float4* __restrict__ u4)
{
  __shared__ float4 sM[2 * APW4 + SF4];   // 1269 f4 = 20304 B

  const int bid  = blockIdx.x;
  const int pair = bid & 7;                 // 512-col window pair
  const int rw0  = (bid >> 3) * RPW;        // 8 rows, shared by both waves
  const int w    = threadIdx.x >> 6;        // wave id: tile 2*pair+w
  const int lane = threadIdx.x & 63;
  const int j    = lane & 7;                // row-local (quarter-wave: 8 rows)
  const int q    = lane >> 3;               // chunk-local 0..7
  const int cw   = pair * 2 + w;            // this wave's 256-col window

  float4* __restrict__ sA = sM + w * APW4;  // wave-private [RPW][ST4]
  float4* __restrict__ sF = sM + 2 * APW4;  // f pair window (idempotent writes)

  // ---- stage f window (each wave writes all; identical values) ----
  {
    const int fb4 = pair * 128 - 3;
    #pragma unroll
    for (int it = 0; it < 3; ++it) {
      const int idx = lane + it * 64;
      if (idx < SF4) {
        int g4 = fb4 + idx;
        g4 = (g4 < 0) ? 0 : ((g4 > 1023) ? 1023 : g4);
        sF[idx] = f4[g4];
      }
    }
  }

  // ---- stage own alpha panel; unroll capped at 3 ----
  {
    const int cb4 = cw * 64 - 3;
    #pragma unroll 3
    for (int it = 0; it < 9; ++it) {
      int idx = lane + it * 64;
      if (idx > RPW * F4PR - 1) idx = RPW * F4PR - 1;   // dup, unused
      const int row = idx / F4PR;
      const int c4  = idx - row * F4PR;
      int g4 = cb4 + c4;
      g4 = (g4 < 0) ? 0 : ((g4 > 1023) ? 1023 : g4);    // dups unused
      sA[row * ST4 + c4] = alpha4[(size_t)(rw0 + row) * 1024 + g4];
    }
  }
  // no __syncthreads: wave reads only its own sA + its own sF writes

  // Mobius step: rolling (asq = a0*a0 from prev iteration), chain (D,N,P).
  //   c8 = ap1*(0.125*ap1+0.25); b8 = max(fma(asq,a0,5),0.01)*0.125
  //   nsq = am1^2; a28 = nsq*0.125
  //   Nn = a28*D; t2 = f8*D; D = fma(b8,D,-c8*N); P = fma(-c8,P,t2); N = Nn
#define MSTEP(am1v, fiv)                                         \
  {                                                              \
    const float c8  = ap1 * fmaf(0.125f, ap1, 0.25f);            \
    const float b8  = fmaxf(fmaf(asq, a0, 5.0f), 0.01f) * 0.125f;\
    const float nsq = (am1v) * (am1v);                           \
    const float t1  = c8 * Nc;                                   \
    const float t2  = (fiv) * 0.125f * Dc;                       \
    const float Nn  = nsq * 0.125f * Dc;                         \
    Dc = fmaf(b8, Dc, -t1);                                      \
    Pc = fmaf(-c8, Pc, t2);                                      \
    Nc = Nn;                                                     \
    ap1 = a0; a0 = (am1v); asq = nsq;                            \
  }

  // ---- solve this wave's tile ----
  const int  kk    = cw * 8 + q;
  const bool first = (kk == 0);
  const bool last  = (kk == kNC - 1);
  const int  f4b   = first ? 3 : (q * 8 + 1);
  const int  fOff  = w * 64;
  const float4* __restrict__ A4 = sA + j * ST4;

  h2v gp_pk[kR / 2], ep_pk[kR / 2];     // fp16-packed stores: 40 regs
  float Dc = 1.0f, Nc = 0.0f, Pc = 0.0f;
  float ap1 = 0.0f;                     // first c8*N = c8*0: seed irrelevant
  const int ghi = last ? 9 : GHI;
  float4 curA = A4[f4b + ghi];
  float4 lowA = A4[f4b + ghi - 1];
  float4 fcur = sF[fOff + f4b + ghi];
  float4 flow = sF[fOff + f4b + ghi - 1];
  float a0  = curA.w;
  float asq = a0 * a0;

  if (!last) {
    #pragma unroll
    for (int g = GHI; g >= 10; --g) {
      const float4 pA = A4[f4b + g - 2];
      const float4 pF = sF[fOff + f4b + g - 2];
      MSTEP(curA.z, fcur.w)
      MSTEP(curA.y, fcur.z)
      MSTEP(curA.x, fcur.y)
      MSTEP(lowA.w, fcur.x)
      curA = lowA; lowA = pA; fcur = flow; flow = pF;
    }
  }

  #pragma unroll
  for (int g = 9; g >= 0; --g) {
    int pidx = f4b + g - 2;
    if (pidx < 0) pidx = 0;              // value unused when clamped
    const float4 pA = A4[pidx];
    const float4 pF = sF[fOff + pidx];
    float lw = lowA.w;
    if (g == 0 && first) lw = 0.0f;      // a_0 = 0
    // per stored position: off-chain rcp(D) + 2 muls feed the fp16 pack
    MSTEP(curA.z, fcur.w)
    float rd3 = __builtin_amdgcn_rcpf(Dc);
    const float g3_ = Pc * rd3, e3_ = Nc * rd3;
    MSTEP(curA.y, fcur.z)
    float rd2 = __builtin_amdgcn_rcpf(Dc);
    const float g2_ = Pc * rd2, e2_ = Nc * rd2;
    MSTEP(curA.x, fcur.y)
    float rd1 = __builtin_amdgcn_rcpf(Dc);
    const float g1_ = Pc * rd1, e1_ = Nc * rd1;
    MSTEP(lw,     fcur.x)
    float rd0 = __builtin_amdgcn_rcpf(Dc);
    const float g0_ = Pc * rd0, e0_ = Nc * rd0;
    gp_pk[2 * g + 1] = __builtin_amdgcn_cvt_pkrtz(g2_, g3_);
    gp_pk[2 * g]     = __builtin_amdgcn_cvt_pkrtz(g0_, g1_);
    ep_pk[2 * g + 1] = __builtin_amdgcn_cvt_pkrtz(e2_, e3_);
    ep_pk[2 * g]     = __builtin_amdgcn_cvt_pkrtz(e0_, e1_);
    curA = lowA; lowA = pA; fcur = flow; flow = pF;
  }

  // ---- substitution into own panel (overlays sA), then nt dump ----
  const int tmin = first ? 0 : kHL;
  float up = 0.0f;
  float4 pk;
  #pragma unroll
  for (int t = 0; t < kR; ++t) {
    const float gpv = (float)gp_pk[t >> 1][t & 1];
    const float epv = (float)ep_pk[t >> 1][t & 1];
    const float uv = fmaf(-epv, up, gpv);
    up = uv;
    const int ph = t & 3;
    if      (ph == 0) pk.x = uv;
    else if (ph == 1) pk.y = uv;
    else if (ph == 2) pk.z = uv;
    else {
      pk.w = uv;
      if (t - 3 >= tmin && t < tmin + kCH) {
        sA[j * ST4 + q * 8 + ((t - 3 - tmin) >> 2)] = pk;
      }
    }
  }

  #pragma unroll
  for (int it = 0; it < RPW; ++it) {
    const float4 v = sA[it * ST4 + lane];
    f4v vv; vv.x = v.x; vv.y = v.y; vv.z = v.z; vv.w = v.w;
    __builtin_nontemporal_store(vv, reinterpret_cast<f4v*>(
        u4 + (size_t)(rw0 + it) * 1024 + cw * 64 + lane));
  }

#undef MSTEP
}

extern "C" void kernel_launch(void* const* d_in, const int* in_sizes, int n_in,
                              void* d_out, int out_size, void* d_ws, size_t ws_size,
                              hipStream_t stream) {
  const float4* alpha = (const float4*)d_in[0];
  const float4* f     = (const float4*)d_in[1];
  float4*       uo    = (float4*)d_out;
  // grid: 1024 row-groups (8 rows) x 8 window-pairs (512 cols) = 8192 blocks
  thomas_v20<<<dim3(8192), THREADS, 0, stream>>>(alpha, f, uo);
}